// Round 1
// baseline (205.142 us; speedup 1.0000x reference)
//
#include <hip/hip_runtime.h>
#include <hip/hip_bf16.h>
#include <stdint.h>

// HashEmbedding2: out[b, 0:56]  = sum_h w[b,h] * table[idx0[b,h], :]
//                 out[b, 56:64] = w[b, :]
// idx0[b,h] = (x[b]*a0[h] + b0[h]) mod 2^20   (B_ROWS = 1048576 = 2^20)
// idx1[b]   = (x[b]*a1 + b1) mod 149796
// w[b,h]    = weights[idx1[b], h]

#define BATCH   524288
#define DD      56
#define NHASH   8
#define BROWS_MASK 0xFFFFFu
#define KROWS   149796u
#define WAVES_PER_BLOCK 4

__global__ __launch_bounds__(256) void hash_embed_kernel(
    const int* __restrict__ x,
    const float* __restrict__ table,
    const float* __restrict__ weights,
    const int* __restrict__ a0,
    const int* __restrict__ b0,
    const int* __restrict__ a1,
    const int* __restrict__ b1,
    float* __restrict__ out)
{
    const int lane = threadIdx.x & 63;
    const int wave = threadIdx.x >> 6;
    const int b = blockIdx.x * WAVES_PER_BLOCK + wave;
    if (b >= BATCH) return;

    const uint32_t xu = (uint32_t)x[b];

    // --- idx1 and w row ---
    const uint32_t h1 = xu * (uint32_t)a1[0] + (uint32_t)b1[0];
    const uint32_t idx1 = h1 % KROWS;

    float w[NHASH];
    const float* wrow = weights + (size_t)idx1 * NHASH;
#pragma unroll
    for (int h = 0; h < NHASH; ++h) w[h] = wrow[h];

    // --- 8 table row indices (computed redundantly per lane; cheap) ---
    uint32_t idx0[NHASH];
#pragma unroll
    for (int h = 0; h < NHASH; ++h) {
        idx0[h] = (xu * (uint32_t)a0[h] + (uint32_t)b0[h]) & BROWS_MASK;
    }

    float res;
    if (lane < DD) {
        // lanes 0..55: coalesced 224B gather per row, 8 rows, weighted sum
        float acc = 0.0f;
#pragma unroll
        for (int h = 0; h < NHASH; ++h) {
            const float v = table[(uint32_t)(idx0[h] * DD) + (uint32_t)lane];
            acc = fmaf(w[h], v, acc);
        }
        res = acc;
    } else {
        // lanes 56..63: pass through w
        res = w[lane - DD];
    }

    out[(size_t)b * 64 + lane] = res;
}

extern "C" void kernel_launch(void* const* d_in, const int* in_sizes, int n_in,
                              void* d_out, int out_size, void* d_ws, size_t ws_size,
                              hipStream_t stream)
{
    const int*   x       = (const int*)d_in[0];
    const float* table   = (const float*)d_in[1];
    const float* weights = (const float*)d_in[2];
    const int*   a0      = (const int*)d_in[3];
    const int*   b0      = (const int*)d_in[4];
    const int*   a1      = (const int*)d_in[5];
    const int*   b1      = (const int*)d_in[6];
    float* out = (float*)d_out;

    const int grid = BATCH / WAVES_PER_BLOCK;  // 131072
    hash_embed_kernel<<<grid, 256, 0, stream>>>(x, table, weights, a0, b0, a1, b1, out);
}